// Round 3
// baseline (195.036 us; speedup 1.0000x reference)
//
#include <hip/hip_runtime.h>
#include <hip/hip_fp16.h>

typedef _Float16 f16x8 __attribute__((ext_vector_type(8)));
typedef _Float16 f16x4 __attribute__((ext_vector_type(4)));
typedef float f32x4 __attribute__((ext_vector_type(4)));

__device__ __forceinline__ f32x4 ntld4(const float* p) {
    return __builtin_nontemporal_load((const f32x4*)p);
}
__device__ __forceinline__ float ntld1(const float* p) {
    return __builtin_nontemporal_load(p);
}
__device__ __forceinline__ f32x4 ld4(const float* p) {
    return *(const f32x4*)p;
}
__device__ __forceinline__ void ntst4(float* p, f32x4 v) {
    __builtin_nontemporal_store(v, (f32x4*)p);
}

// ---------------------------------------------------------------------------
// Mega kernel. Blocks [0, nbR): reduction over key/value tiles.
// Blocks [nbR, nbR+8192): fused attention, h-major (concurrent blocks share
// one head's mk/mv -> L2-hot) with streaming nt hints on q and outputs.
// Staging: thread t owns LDS row d=t&63, n-chunk t>>6; 16 coalesced scalar
// global loads -> 2x f16x8 LDS row stores (conflict-free).
// MFMA operand order chosen so C-fragments are d-contiguous -> f32x4 stores.
// ---------------------------------------------------------------------------
__global__ __launch_bounds__(256) void mega(
    const float* __restrict__ q,   const float* __restrict__ key,
    const float* __restrict__ val, const float* __restrict__ mk,
    const float* __restrict__ mnorm, const float* __restrict__ mv,
    float* __restrict__ out_mo, float* __restrict__ out_sc,
    float* __restrict__ skp, float* __restrict__ svp, float* __restrict__ pbp,
    const int nbR)
{
    __shared__ union SM {
        struct { _Float16 qT[64][72]; _Float16 mkT[64][72]; _Float16 sT[64][72]; } f;
        struct { float ktile[64][68]; float red[256]; float ks[64]; } r;
    } sm;

    const int t   = threadIdx.x;
    const int bid = blockIdx.x;

    if (bid < nbR) {
        // ================= reduction path =================
        const int r0 = t >> 4;
        const int c0 = (t & 15) << 2;
        f32x4 ska[4] = {}; f32x4 sva[4] = {};
        float pba[4] = {0.f, 0.f, 0.f, 0.f};
        f32x4 ka[4], va[4];
        int i = bid;
#pragma unroll
        for (int qq = 0; qq < 4; ++qq) {
            const int row = r0 + 16 * qq;
            ka[qq] = ntld4(key + (size_t)i * 4096 + row * 64 + c0);
            va[qq] = ntld4(val + (size_t)i * 4096 + row * 64 + c0);
        }
        while (true) {
            const int inx = i + nbR;
            const bool more = (inx < 8192);
            f32x4 kn4[4], vn4[4];
            if (more) {
#pragma unroll
                for (int qq = 0; qq < 4; ++qq) {
                    const int row = r0 + 16 * qq;
                    kn4[qq] = ntld4(key + (size_t)inx * 4096 + row * 64 + c0);
                    vn4[qq] = ntld4(val + (size_t)inx * 4096 + row * 64 + c0);
                }
            }
#pragma unroll
            for (int qq = 0; qq < 4; ++qq) {
                const int row = r0 + 16 * qq;
                ska[qq] += ka[qq];
                sva[qq] += va[qq];
                *(f32x4*)&sm.r.ktile[row][c0] = ka[qq];
            }
            __syncthreads();
            {   // ks[d] = sum_n ktile[n][d]
                const int d  = t & 63;
                const int rr = (t >> 6) * 16;
                float p = 0.f;
#pragma unroll
                for (int r = 0; r < 16; ++r) p += sm.r.ktile[rr + r][d];
                sm.r.red[t] = p;
            }
            __syncthreads();
            if (t < 64)
                sm.r.ks[t] = sm.r.red[t] + sm.r.red[t + 64] + sm.r.red[t + 128] + sm.r.red[t + 192];
            __syncthreads();
#pragma unroll
            for (int qq = 0; qq < 4; ++qq) {
                float pq = va[qq][0] * sm.r.ks[c0]     + va[qq][1] * sm.r.ks[c0 + 1]
                         + va[qq][2] * sm.r.ks[c0 + 2] + va[qq][3] * sm.r.ks[c0 + 3];
                pq += __shfl_xor(pq, 1);
                pq += __shfl_xor(pq, 2);
                pq += __shfl_xor(pq, 4);
                pq += __shfl_xor(pq, 8);
                pba[qq] += pq;
            }
            if (!more) break;
#pragma unroll
            for (int qq = 0; qq < 4; ++qq) { ka[qq] = kn4[qq]; va[qq] = vn4[qq]; }
            i = inx;
        }
        const size_t pb4 = (size_t)bid * 4096;
#pragma unroll
        for (int qq = 0; qq < 4; ++qq) {
            *(f32x4*)(skp + pb4 + 4 * t + 1024 * qq) = ska[qq];
            *(f32x4*)(svp + pb4 + 4 * t + 1024 * qq) = sva[qq];
        }
        if ((t & 15) == 0) {
#pragma unroll
            for (int qq = 0; qq < 4; ++qq)
                pbp[bid * 64 + r0 + 16 * qq] = pba[qq];
        }
        return;
    }

    // ================= fused attention path =================
    const int fid = bid - nbR;
    const int h   = fid >> 7;          // h-major
    const int b   = fid & 127;
    const int bh  = b * 64 + h;
    const float* qb  = q  + (size_t)bh * 4096;
    const float* mkb = mk + h * 4096;
    const float* mvb = mv + h * 4096;

    const int w  = t >> 6;   // wave id
    const int l  = t & 63;
    const int lr = l & 15;
    const int lk = l >> 4;
    const size_t gbase = (size_t)bh * 4096;

    // mv A... (B operand) fragments: rows n = 16w+lr, k-cols lk*8+{0..7}+32kn
    f32x4 mva[4];
    {
        const float* rowp = mvb + (16 * w + lr) * 64 + lk * 8;
        mva[0] = ld4(rowp);      mva[1] = ld4(rowp + 4);
        mva[2] = ld4(rowp + 32); mva[3] = ld4(rowp + 36);
    }

    // ---- staging: thread owns LDS row d = t&63, n-chunk nc = t>>6 ----
    {
        const int d  = t & 63;
        const int n0 = (t >> 6) * 16;
        float qv[16], kv[16];
#pragma unroll
        for (int i = 0; i < 16; ++i) {
            qv[i] = ntld1(qb + (n0 + i) * 64 + d);   // coalesced: lanes = consecutive d
            kv[i] = mkb[(n0 + i) * 64 + d];
        }
        f16x8 qh0, qh1, kh0, kh1;
#pragma unroll
        for (int i = 0; i < 8; ++i) {
            qh0[i] = (_Float16)qv[i];     qh1[i] = (_Float16)qv[i + 8];
            kh0[i] = (_Float16)kv[i];     kh1[i] = (_Float16)kv[i + 8];
        }
        *(f16x8*)&sm.f.qT [d][n0]     = qh0;
        *(f16x8*)&sm.f.qT [d][n0 + 8] = qh1;
        *(f16x8*)&sm.f.mkT[d][n0]     = kh0;
        *(f16x8*)&sm.f.mkT[d][n0 + 8] = kh1;
    }
    __syncthreads();

    // S[m,d]: acc[di] = mfma(A = qT rows 16di+lr, B = mkT rows 16w+lr)
    //   -> D rows = d (16di+4lk+r), cols = m (16w+lr)
    f32x4 acc[4] = {};
#pragma unroll
    for (int kn = 0; kn < 2; ++kn) {
        f16x8 bfr = *(const f16x8*)&sm.f.mkT[16 * w + lr][kn * 32 + lk * 8];
#pragma unroll
        for (int di = 0; di < 4; ++di) {
            f16x8 afr = *(const f16x8*)&sm.f.qT[16 * di + lr][kn * 32 + lk * 8];
            acc[di] = __builtin_amdgcn_mfma_f32_16x16x32_f16(afr, bfr, acc[di], 0, 0, 0);
        }
    }

    // epilogue 1: scale, f32x4 store to out_sc, f16 scatter into sT
    const int m = 16 * w + lr;
#pragma unroll
    for (int di = 0; di < 4; ++di) {
        const int d0 = 16 * di + 4 * lk;
        f32x4 nv = ld4(mnorm + d0);
        f32x4 sv;
#pragma unroll
        for (int r = 0; r < 4; ++r) {
            sv[r] = acc[di][r] / (nv[r] + 1e-6f);
            sm.f.sT[d0 + r][m] = (_Float16)sv[r];
        }
        ntst4(out_sc + gbase + (size_t)m * 64 + d0, sv);
    }
    __syncthreads();

    // O[n,d]: acc2[di] = mfma(A = sT rows 16di+lr, B = mv rows 16w+lr)
    f16x8 b2[2];
#pragma unroll
    for (int kn = 0; kn < 2; ++kn) {
        f16x8 vv;
#pragma unroll
        for (int j = 0; j < 4; ++j) {
            vv[j]     = (_Float16)mva[2 * kn][j];
            vv[j + 4] = (_Float16)mva[2 * kn + 1][j];
        }
        b2[kn] = vv;
    }
    f32x4 acc2[4] = {};
#pragma unroll
    for (int kn = 0; kn < 2; ++kn) {
#pragma unroll
        for (int di = 0; di < 4; ++di) {
            f16x8 afr = *(const f16x8*)&sm.f.sT[16 * di + lr][kn * 32 + lk * 8];
            acc2[di] = __builtin_amdgcn_mfma_f32_16x16x32_f16(afr, b2[kn], acc2[di], 0, 0, 0);
        }
    }
#pragma unroll
    for (int di = 0; di < 4; ++di) {
        const int d0 = 16 * di + 4 * lk;
        f32x4 ov;
#pragma unroll
        for (int r = 0; r < 4; ++r) ov[r] = acc2[di][r];
        ntst4(out_mo + gbase + (size_t)m * 64 + d0, ov);
    }
}

// Stage 2: NC n-chunks x 33 strips -> p2[NC][8256]
#define NCHUNK 8
__global__ __launch_bounds__(256) void reduce2(
    const float* __restrict__ skp, const float* __restrict__ svp,
    const float* __restrict__ pbp, float* __restrict__ p2,
    const int nbR, const int clen)
{
    const int bi = blockIdx.x;
    const int c  = bi / 33;
    const int e  = (bi % 33) * 256 + threadIdx.x;
    if (e >= 8256) return;
    int n0 = c * clen;
    int n1 = n0 + clen; if (n1 > nbR) n1 = nbR;
    float s = 0.f;
    if (e < 4096) {
        for (int n = n0; n < n1; ++n) s += skp[(size_t)n * 4096 + e];
    } else if (e < 8192) {
        const int e2 = e - 4096;
        for (int n = n0; n < n1; ++n) s += svp[(size_t)n * 4096 + e2];
    } else {
        const int e2 = e - 8192;
        for (int n = n0; n < n1; ++n) s += pbp[n * 64 + e2];
    }
    p2[c * 8256 + e] = s;
}

// Stage 3: finalize — sum the NC chunks (phase A, into LDS), then norms,
// compression factor, and the two small outputs.
__global__ __launch_bounds__(256) void finalize(
    const float* __restrict__ p2, const float* __restrict__ mnorm,
    const float* __restrict__ crate,
    float* __restrict__ out_nmk, float* __restrict__ out_nmn)
{
    __shared__ float tot[8256];
    __shared__ float fac_s[64];
    const int t = threadIdx.x;
    for (int e = t; e < 8256; e += 256) {
        float s = 0.f;
#pragma unroll
        for (int c = 0; c < NCHUNK; ++c) s += p2[c * 8256 + e];
        tot[e] = s;
    }
    __syncthreads();
    const float* sk_tot = tot;
    const float* sv_tot = tot + 4096;
    const float* pb_tot = tot + 8192;
    if (t < 64) {
        float ss = 0.f;
#pragma unroll 8
        for (int d = 0; d < 64; ++d) {
            float mkm = sk_tot[t * 64 + d] * (1.0f / 8192.0f);
            ss += mkm * mkm;
        }
        const float nmn = mnorm[t] + sqrtf(ss);
        float v = nmn;
        for (int off = 32; off; off >>= 1) v += __shfl_xor(v, off);
        const float mean = v * (1.0f / 64.0f);
        const float f = (mean > 0.9f) ? crate[t] : 1.0f;
        fac_s[t] = f;
        out_nmn[t] = nmn * f;
    }
    __syncthreads();
    for (int e = t; e < 4096; e += 256) {
        const int j = e >> 6;
        const float mb = pb_tot[j] * (1.0f / 524288.0f);   // mean binding
        const float mvv = sv_tot[e] * (1.0f / 8192.0f);    // mean value
        out_nmk[e] = mb * mvv * fac_s[j];
    }
}

extern "C" void kernel_launch(void* const* d_in, const int* in_sizes, int n_in,
                              void* d_out, int out_size, void* d_ws, size_t ws_size,
                              hipStream_t stream) {
    const float* q  = (const float*)d_in[0];
    const float* k  = (const float*)d_in[1];
    const float* v  = (const float*)d_in[2];
    const float* mk = (const float*)d_in[3];
    const float* mn = (const float*)d_in[4];
    const float* mv = (const float*)d_in[5];
    const float* cr = (const float*)d_in[6];

    float* out     = (float*)d_out;
    float* out_mo  = out;                    // [128,64,64,64]
    float* out_sc  = out + 33554432;         // [128,64,64,64]
    float* out_nmk = out + 67108864;         // [64,64]
    float* out_nmn = out + 67112960;         // [64]

    float* ws   = (float*)d_ws;
    float* p2   = ws;                        // NCHUNK*8256
    float* part = ws + NCHUNK * 8256;
    const size_t wsf = ws_size / 4;
    const size_t used = NCHUNK * 8256;
    const size_t avail = (wsf > used) ? (wsf - used) : 0;
    int nb = (int)(avail / 8256);
    if (nb > 1024) nb = 1024;
    if (nb < 1)    nb = 1;
    float* skp = part;
    float* svp = part + (size_t)nb * 4096;
    float* pbp = svp  + (size_t)nb * 4096;
    const int clen = (nb + NCHUNK - 1) / NCHUNK;

    hipLaunchKernelGGL(mega, dim3(nb + 8192), dim3(256), 0, stream,
                       q, k, v, mk, mn, mv, out_mo, out_sc, skp, svp, pbp, nb);
    hipLaunchKernelGGL(reduce2, dim3(33 * NCHUNK), dim3(256), 0, stream,
                       skp, svp, pbp, p2, nb, clen);
    hipLaunchKernelGGL(finalize, dim3(1), dim3(256), 0, stream,
                       p2, mn, cr, out_nmk, out_nmn);
}

// Round 4
// 161.483 us; speedup vs baseline: 1.2078x; 1.2078x over previous
//
#include <hip/hip_runtime.h>
#include <hip/hip_fp16.h>

typedef _Float16 f16x8 __attribute__((ext_vector_type(8)));
typedef _Float16 f16x4 __attribute__((ext_vector_type(4)));
typedef float f32x4 __attribute__((ext_vector_type(4)));

__device__ __forceinline__ f32x4 ntld4(const float* p) {
    return __builtin_nontemporal_load((const f32x4*)p);
}
__device__ __forceinline__ float ntld1(const float* p) {
    return __builtin_nontemporal_load(p);
}
__device__ __forceinline__ f32x4 ld4(const float* p) {
    return *(const f32x4*)p;
}
__device__ __forceinline__ void st4(float* p, f32x4 v) {
    *(f32x4*)p = v;
}

// ---------------------------------------------------------------------------
// Mega kernel. Blocks [0, nbR): reduction over key/value tiles.
// Blocks [nbR, nbR+8192): fused attention, h-major (concurrent blocks share
// one head's mk/mv -> L2-hot), nt hints on streaming loads only.
// LDS: 18,688 B (sT aliases qT) -> 7-8 blocks/CU for latency hiding.
// ---------------------------------------------------------------------------
__global__ __launch_bounds__(256) void mega(
    const float* __restrict__ q,   const float* __restrict__ key,
    const float* __restrict__ val, const float* __restrict__ mk,
    const float* __restrict__ mnorm, const float* __restrict__ mv,
    float* __restrict__ out_mo, float* __restrict__ out_sc,
    float* __restrict__ skp, float* __restrict__ svp, float* __restrict__ pbp,
    const int nbR)
{
    __shared__ union SM {
        struct { _Float16 qT[64][72]; _Float16 mkT[64][72]; } f;   // sT aliases qT
        struct { float ktile[64][68]; float red[256]; float ks[64]; } r;
    } sm;

    const int t   = threadIdx.x;
    const int bid = blockIdx.x;

    if (bid < nbR) {
        // ================= reduction path =================
        const int r0 = t >> 4;
        const int c0 = (t & 15) << 2;
        f32x4 ska[4] = {}; f32x4 sva[4] = {};
        float pba[4] = {0.f, 0.f, 0.f, 0.f};
        f32x4 ka[4], va[4];
        int i = bid;
#pragma unroll
        for (int qq = 0; qq < 4; ++qq) {
            const int row = r0 + 16 * qq;
            ka[qq] = ntld4(key + (size_t)i * 4096 + row * 64 + c0);
            va[qq] = ntld4(val + (size_t)i * 4096 + row * 64 + c0);
        }
        while (true) {
            const int inx = i + nbR;
            const bool more = (inx < 8192);
            f32x4 kn4[4], vn4[4];
            if (more) {
#pragma unroll
                for (int qq = 0; qq < 4; ++qq) {
                    const int row = r0 + 16 * qq;
                    kn4[qq] = ntld4(key + (size_t)inx * 4096 + row * 64 + c0);
                    vn4[qq] = ntld4(val + (size_t)inx * 4096 + row * 64 + c0);
                }
            }
#pragma unroll
            for (int qq = 0; qq < 4; ++qq) {
                const int row = r0 + 16 * qq;
                ska[qq] += ka[qq];
                sva[qq] += va[qq];
                *(f32x4*)&sm.r.ktile[row][c0] = ka[qq];
            }
            __syncthreads();
            {   // ks[d] = sum_n ktile[n][d]
                const int d  = t & 63;
                const int rr = (t >> 6) * 16;
                float p = 0.f;
#pragma unroll
                for (int r = 0; r < 16; ++r) p += sm.r.ktile[rr + r][d];
                sm.r.red[t] = p;
            }
            __syncthreads();
            if (t < 64)
                sm.r.ks[t] = sm.r.red[t] + sm.r.red[t + 64] + sm.r.red[t + 128] + sm.r.red[t + 192];
            __syncthreads();
#pragma unroll
            for (int qq = 0; qq < 4; ++qq) {
                float pq = va[qq][0] * sm.r.ks[c0]     + va[qq][1] * sm.r.ks[c0 + 1]
                         + va[qq][2] * sm.r.ks[c0 + 2] + va[qq][3] * sm.r.ks[c0 + 3];
                pq += __shfl_xor(pq, 1);
                pq += __shfl_xor(pq, 2);
                pq += __shfl_xor(pq, 4);
                pq += __shfl_xor(pq, 8);
                pba[qq] += pq;
            }
            if (!more) break;
#pragma unroll
            for (int qq = 0; qq < 4; ++qq) { ka[qq] = kn4[qq]; va[qq] = vn4[qq]; }
            i = inx;
        }
        const size_t pb4 = (size_t)bid * 4096;
#pragma unroll
        for (int qq = 0; qq < 4; ++qq) {
            *(f32x4*)(skp + pb4 + 4 * t + 1024 * qq) = ska[qq];
            *(f32x4*)(svp + pb4 + 4 * t + 1024 * qq) = sva[qq];
        }
        if ((t & 15) == 0) {
#pragma unroll
            for (int qq = 0; qq < 4; ++qq)
                pbp[bid * 64 + r0 + 16 * qq] = pba[qq];
        }
        return;
    }

    // ================= fused attention path =================
    const int fid = bid - nbR;
    const int h   = fid >> 7;          // h-major
    const int b   = fid & 127;
    const int bh  = b * 64 + h;
    const float* qb  = q  + (size_t)bh * 4096;
    const float* mkb = mk + h * 4096;
    const float* mvb = mv + h * 4096;

    const int w  = t >> 6;   // wave id
    const int l  = t & 63;
    const int lr = l & 15;
    const int lk = l >> 4;
    const size_t gbase = (size_t)bh * 4096;

    // ---- staging: thread owns LDS row d=t&63, n-chunk t>>6; streamed halves
    {
        const int d  = t & 63;
        const int n0 = (t >> 6) * 16;
#pragma unroll
        for (int half = 0; half < 2; ++half) {
            const int nh = n0 + 8 * half;
            float qv[8], kv[8];
#pragma unroll
            for (int i = 0; i < 8; ++i) qv[i] = ntld1(qb + (nh + i) * 64 + d);
#pragma unroll
            for (int i = 0; i < 8; ++i) kv[i] = mkb[(nh + i) * 64 + d];
            f16x8 qh, kh;
#pragma unroll
            for (int i = 0; i < 8; ++i) { qh[i] = (_Float16)qv[i]; kh[i] = (_Float16)kv[i]; }
            *(f16x8*)&sm.f.qT [d][nh] = qh;
            *(f16x8*)&sm.f.mkT[d][nh] = kh;
        }
    }
    __syncthreads();

    // phase 1: S[m,d] -> acc[di] rows = d (16di+4lk+r), cols = m (16w+lr)
    f32x4 acc[4] = {};
#pragma unroll
    for (int kn = 0; kn < 2; ++kn) {
        f16x8 bfr = *(const f16x8*)&sm.f.mkT[16 * w + lr][kn * 32 + lk * 8];
#pragma unroll
        for (int di = 0; di < 4; ++di) {
            f16x8 afr = *(const f16x8*)&sm.f.qT[16 * di + lr][kn * 32 + lk * 8];
            acc[di] = __builtin_amdgcn_mfma_f32_16x16x32_f16(afr, bfr, acc[di], 0, 0, 0);
        }
    }
    __syncthreads();   // all qT/mkT reads done; qT region reusable as sT

    // mv B-operand fragments (L2-hot), loaded while epilogue runs
    f32x4 mva[4];
    {
        const float* rowp = mvb + (16 * w + lr) * 64 + lk * 8;
        mva[0] = ld4(rowp);      mva[1] = ld4(rowp + 4);
        mva[2] = ld4(rowp + 32); mva[3] = ld4(rowp + 36);
    }

    // epilogue 1: scale via v_rcp, f32x4 store to out_sc, f16 scatter into sT
    _Float16* sT = &sm.f.qT[0][0];     // sT[d][m] at sT[d*72+m]
    const int m = 16 * w + lr;
#pragma unroll
    for (int di = 0; di < 4; ++di) {
        const int d0 = 16 * di + 4 * lk;
        f32x4 nv = ld4(mnorm + d0);
        f32x4 sv;
#pragma unroll
        for (int r = 0; r < 4; ++r) {
            sv[r] = acc[di][r] * __builtin_amdgcn_rcpf(nv[r] + 1e-6f);
            sT[(d0 + r) * 72 + m] = (_Float16)sv[r];
        }
        st4(out_sc + gbase + (size_t)m * 64 + d0, sv);
    }
    __syncthreads();

    // phase 2: O[n,d] = sum_m sT[d][m] * mv[n][m]
    f16x8 b2[2];
#pragma unroll
    for (int kn = 0; kn < 2; ++kn) {
        f16x8 vv;
#pragma unroll
        for (int j = 0; j < 4; ++j) {
            vv[j]     = (_Float16)mva[2 * kn][j];
            vv[j + 4] = (_Float16)mva[2 * kn + 1][j];
        }
        b2[kn] = vv;
    }
    f32x4 acc2[4] = {};
#pragma unroll
    for (int kn = 0; kn < 2; ++kn) {
#pragma unroll
        for (int di = 0; di < 4; ++di) {
            f16x8 afr = *(const f16x8*)(sT + (16 * di + lr) * 72 + kn * 32 + lk * 8);
            acc2[di] = __builtin_amdgcn_mfma_f32_16x16x32_f16(afr, b2[kn], acc2[di], 0, 0, 0);
        }
    }
#pragma unroll
    for (int di = 0; di < 4; ++di) {
        const int d0 = 16 * di + 4 * lk;
        f32x4 ov;
#pragma unroll
        for (int r = 0; r < 4; ++r) ov[r] = acc2[di][r];
        st4(out_mo + gbase + (size_t)m * 64 + d0, ov);
    }
}

// Stage 2: NC n-chunks x 33 strips -> p2[NC][8256]
#define NCHUNK 8
__global__ __launch_bounds__(256) void reduce2(
    const float* __restrict__ skp, const float* __restrict__ svp,
    const float* __restrict__ pbp, float* __restrict__ p2,
    const int nbR, const int clen)
{
    const int bi = blockIdx.x;
    const int c  = bi / 33;
    const int e  = (bi % 33) * 256 + threadIdx.x;
    if (e >= 8256) return;
    int n0 = c * clen;
    int n1 = n0 + clen; if (n1 > nbR) n1 = nbR;
    float s = 0.f;
    if (e < 4096) {
        for (int n = n0; n < n1; ++n) s += skp[(size_t)n * 4096 + e];
    } else if (e < 8192) {
        const int e2 = e - 4096;
        for (int n = n0; n < n1; ++n) s += svp[(size_t)n * 4096 + e2];
    } else {
        const int e2 = e - 8192;
        for (int n = n0; n < n1; ++n) s += pbp[n * 64 + e2];
    }
    p2[c * 8256 + e] = s;
}

// Stage 3: finalize — sum the NC chunks, norms, compression factor, outputs.
__global__ __launch_bounds__(256) void finalize(
    const float* __restrict__ p2, const float* __restrict__ mnorm,
    const float* __restrict__ crate,
    float* __restrict__ out_nmk, float* __restrict__ out_nmn)
{
    __shared__ float tot[8256];
    __shared__ float fac_s[64];
    const int t = threadIdx.x;
    for (int e = t; e < 8256; e += 256) {
        float s = 0.f;
#pragma unroll
        for (int c = 0; c < NCHUNK; ++c) s += p2[c * 8256 + e];
        tot[e] = s;
    }
    __syncthreads();
    const float* sk_tot = tot;
    const float* sv_tot = tot + 4096;
    const float* pb_tot = tot + 8192;
    if (t < 64) {
        float ss = 0.f;
#pragma unroll 8
        for (int d = 0; d < 64; ++d) {
            float mkm = sk_tot[t * 64 + d] * (1.0f / 8192.0f);
            ss += mkm * mkm;
        }
        const float nmn = mnorm[t] + sqrtf(ss);
        float v = nmn;
        for (int off = 32; off; off >>= 1) v += __shfl_xor(v, off);
        const float mean = v * (1.0f / 64.0f);
        const float f = (mean > 0.9f) ? crate[t] : 1.0f;
        fac_s[t] = f;
        out_nmn[t] = nmn * f;
    }
    __syncthreads();
    for (int e = t; e < 4096; e += 256) {
        const int j = e >> 6;
        const float mb = pb_tot[j] * (1.0f / 524288.0f);   // mean binding
        const float mvv = sv_tot[e] * (1.0f / 8192.0f);    // mean value
        out_nmk[e] = mb * mvv * fac_s[j];
    }
}

extern "C" void kernel_launch(void* const* d_in, const int* in_sizes, int n_in,
                              void* d_out, int out_size, void* d_ws, size_t ws_size,
                              hipStream_t stream) {
    const float* q  = (const float*)d_in[0];
    const float* k  = (const float*)d_in[1];
    const float* v  = (const float*)d_in[2];
    const float* mk = (const float*)d_in[3];
    const float* mn = (const float*)d_in[4];
    const float* mv = (const float*)d_in[5];
    const float* cr = (const float*)d_in[6];

    float* out     = (float*)d_out;
    float* out_mo  = out;                    // [128,64,64,64]
    float* out_sc  = out + 33554432;         // [128,64,64,64]
    float* out_nmk = out + 67108864;         // [64,64]
    float* out_nmn = out + 67112960;         // [64]

    float* ws   = (float*)d_ws;
    float* p2   = ws;                        // NCHUNK*8256
    float* part = ws + NCHUNK * 8256;
    const size_t wsf = ws_size / 4;
    const size_t used = NCHUNK * 8256;
    const size_t avail = (wsf > used) ? (wsf - used) : 0;
    int nb = (int)(avail / 8256);
    if (nb > 512) nb = 512;
    if (nb < 1)   nb = 1;
    float* skp = part;
    float* svp = part + (size_t)nb * 4096;
    float* pbp = svp  + (size_t)nb * 4096;
    const int clen = (nb + NCHUNK - 1) / NCHUNK;

    hipLaunchKernelGGL(mega, dim3(nb + 8192), dim3(256), 0, stream,
                       q, k, v, mk, mn, mv, out_mo, out_sc, skp, svp, pbp, nb);
    hipLaunchKernelGGL(reduce2, dim3(33 * NCHUNK), dim3(256), 0, stream,
                       skp, svp, pbp, p2, nb, clen);
    hipLaunchKernelGGL(finalize, dim3(1), dim3(256), 0, stream,
                       p2, mn, cr, out_nmk, out_nmn);
}